// Round 8
// baseline (385.797 us; speedup 1.0000x reference)
//
#include <hip/hip_runtime.h>

#define TQY 10
#define TQX 10
#define QST 600        // 6*10*10 sites per quad
#define NSITES 2400    // 4 quads

// LDS map (bytes):
//  [0,19200)      quad tile uint2[2400]: [cq][z 6][y 10][x 10], 4 bf16 channels/site
//  [0,36864)      P bf16 rows (overlays tile after barrier 2), 144B row stride
//  [36864,37888)  alive[256] f32
//  [37888,38912)  msu[256] f32
//
// d_ws (shorts): [0,8192) W1 frags 1024x16B; [8192,10240) W2 frags 256x16B

typedef __attribute__((ext_vector_type(8))) short bf16x8;
typedef __attribute__((ext_vector_type(4))) float f32x4;

__device__ __forceinline__ unsigned short f2bf(float f) {
    unsigned u = __builtin_bit_cast(unsigned, f);
    u += 0x7FFFu + ((u >> 16) & 1u);          // RNE
    return (unsigned short)(u >> 16);
}
__device__ __forceinline__ float blo(unsigned u) { return __builtin_bit_cast(float, u << 16); }
__device__ __forceinline__ float bhi(unsigned u) { return __builtin_bit_cast(float, u & 0xffff0000u); }
__device__ __forceinline__ bf16x8 pack8f(float4 a, float4 b) {
    bf16x8 o;
    o[0] = (short)f2bf(a.x); o[1] = (short)f2bf(a.y);
    o[2] = (short)f2bf(a.z); o[3] = (short)f2bf(a.w);
    o[4] = (short)f2bf(b.x); o[5] = (short)f2bf(b.y);
    o[6] = (short)f2bf(b.z); o[7] = (short)f2bf(b.w);
    return o;
}

// ---- pre-pass: permute W1/W2 into lane-canonical bf16 MFMA fragments in d_ws ----
__global__ __launch_bounds__(256) void permute_w(
    const float* __restrict__ w1, const float* __restrict__ w2,
    unsigned short* __restrict__ wsW)
{
    const int t = threadIdx.x;
    #pragma unroll
    for (int j = 0; j < 4; ++j) {
        int w = t + 256 * j;                 // [0,1024)
        int lane = w & 63, f = (w >> 6) & 3, ch = w >> 8;
        int r16 = lane & 15, g = lane >> 4;
        int row = ch * 32 + 8 * (r16 >> 2) + (r16 & 3) + 4 * (f >> 1);  // E: +0, O: +4
        int col = (f & 1) * 32 + g * 8;                                  // ks half
        const float* src = w1 + row * 64 + col;
        bf16x8 v = pack8f(*(const float4*)src, *(const float4*)(src + 4));
        *(bf16x8*)(wsW + w * 8) = v;
    }
    {
        int w = t;                           // [0,256)
        int lane = w & 63, ch = w >> 6;
        int r16 = lane & 15, g = lane >> 4;
        const float* src = w2 + r16 * 128 + ch * 32 + g * 8;
        bf16x8 v = pack8f(*(const float4*)src, *(const float4*)(src + 4));
        *(bf16x8*)(wsW + 8192 + w * 8) = v;
    }
}

__global__ __launch_bounds__(256, 4) void nca_fused(
    const float* __restrict__ x, const float* __restrict__ rand_u,
    const unsigned short* __restrict__ wsW, const float* __restrict__ b1,
    float* __restrict__ out)
{
    __shared__ __align__(16) char smem[38912];
    uint2*          tq     = (uint2*)smem;
    unsigned short* Ps     = (unsigned short*)smem;       // after barrier 2
    float*          aliveA = (float*)(smem + 36864);
    float*          msuA   = (float*)(smem + 37888);

    const int tid = threadIdx.x;
    const int gx0 = blockIdx.x * 8, gy0 = blockIdx.y * 8;
    const int zb  = blockIdx.z;
    const int b   = zb >> 4, gz0 = (zb & 15) * 4;
    const int xbase = b * (16 * 262144);

    // ---- phase 1: stage channel-quad bf16 tile (zero halo) ----
    for (int i = tid; i < NSITES; i += 256) {
        int cq = i / QST, r = i - cq * QST;
        int z = r / 100, r2 = r - z * 100;
        int y = r2 / 10, xx = r2 - y * 10;
        int gz = gz0 + z - 1, gy = gy0 + y - 1, gxx = gx0 + xx - 1;
        uint2 w = make_uint2(0u, 0u);
        if ((unsigned)gz < 64u && (unsigned)gy < 64u && (unsigned)gxx < 64u) {
            const float* s = x + xbase + cq * (4 * 262144) + gz * 4096 + gy * 64 + gxx;
            w.x = (unsigned)f2bf(s[0])            | ((unsigned)f2bf(s[262144]) << 16);
            w.y = (unsigned)f2bf(s[2 * 262144])   | ((unsigned)f2bf(s[3 * 262144]) << 16);
        }
        tq[i] = w;
    }
    __syncthreads();

    // ---- phase 2: perception, separable Sobel on bf16 quads ----
    const int tx = tid & 7, ty = (tid >> 3) & 7, tz = tid >> 6;
    const int lane = tid & 63, wv = tid >> 6;
    const int g = lane >> 4, r16 = lane & 15;
    const int rowbase = (tz * TQY + ty) * TQX + tx;

    unsigned pk[32];
    float pool3 = -1e30f;

    #pragma unroll
    for (int cq = 0; cq < 4; ++cq) {
        float s1a[4], s2a[4], s3a[4];
        unsigned short ctrs[4];
        #pragma unroll
        for (int e = 0; e < 4; ++e) { s1a[e] = 0.f; s2a[e] = 0.f; s3a[e] = 0.f; }
        #pragma unroll
        for (int i2 = 0; i2 < 3; ++i2) {
            float A[4], Bv[4], Cv[4];
            #pragma unroll
            for (int e = 0; e < 4; ++e) { A[e] = 0.f; Bv[e] = 0.f; Cv[e] = 0.f; }
            #pragma unroll
            for (int j = 0; j < 3; ++j) {
                const uint2* rp = tq + cq * QST + i2 * 100 + j * 10 + rowbase;
                uint2 q0 = rp[0], q1 = rp[1], q2 = rp[2];
                float v0[4] = { blo(q0.x), bhi(q0.x), blo(q0.y), bhi(q0.y) };
                float v1[4] = { blo(q1.x), bhi(q1.x), blo(q1.y), bhi(q1.y) };
                float v2[4] = { blo(q2.x), bhi(q2.x), blo(q2.y), bhi(q2.y) };
                if (cq == 0)   // alpha (c=3) pool, reusing the same taps
                    pool3 = fmaxf(pool3, fmaxf(fmaxf(v0[3], v1[3]), v2[3]));
                if (i2 == 1 && j == 1) {   // center bf16 shorts (ident features)
                    ctrs[0] = (unsigned short)(q1.x & 0xffffu);
                    ctrs[1] = (unsigned short)(q1.x >> 16);
                    ctrs[2] = (unsigned short)(q1.y & 0xffffu);
                    ctrs[3] = (unsigned short)(q1.y >> 16);
                }
                const float wj = (j == 1) ? 2.f : 1.f;
                #pragma unroll
                for (int e = 0; e < 4; ++e) {
                    float rg = fmaf(2.f, v1[e], v0[e] + v2[e]);  // g_x
                    float rd = v2[e] - v0[e];                    // d_x
                    A[e]  = fmaf(wj, rg, A[e]);                  // g_y g_x
                    Cv[e] = fmaf(wj, rd, Cv[e]);                 // g_y d_x
                    if (j == 0) Bv[e] -= rg;                     // d_y g_x
                    if (j == 2) Bv[e] += rg;
                }
            }
            const float wi = (i2 == 1) ? 2.f : 1.f;
            #pragma unroll
            for (int e = 0; e < 4; ++e) {
                if (i2 == 0) s1a[e] -= A[e];                     // d_z (g_y g_x)
                if (i2 == 2) s1a[e] += A[e];
                s2a[e] = fmaf(wi, Bv[e], s2a[e]);                // g_z (d_y g_x)
                s3a[e] = fmaf(wi, Cv[e], s3a[e]);                // g_z (g_y d_x)
            }
        }
        #pragma unroll
        for (int e = 0; e < 4; ++e) {
            int c = 4 * cq + e;
            pk[2 * c]     = (unsigned)ctrs[e]                    | ((unsigned)f2bf(s1a[e] * 0.125f) << 16);
            pk[2 * c + 1] = (unsigned)f2bf(s2a[e] * 0.125f)      | ((unsigned)f2bf(s3a[e] * 0.125f) << 16);
        }
    }
    const float alive = (pool3 > 0.1f) ? 1.f : 0.f;
    const float ru = rand_u[b * 262144 + (gz0 + tz) * 4096 + (gy0 + ty) * 64 + (gx0 + tx)];
    aliveA[tid] = alive;
    msuA[tid]   = (ru <= 0.5f) ? alive : 0.f;
    __syncthreads();   // all waves done reading tile

    // ---- phase 3: write P (bf16) over the tile region ----
    uint4* prow = (uint4*)(smem + tid * 144);
    #pragma unroll
    for (int j = 0; j < 8; ++j)
        prow[j] = make_uint4(pk[4 * j], pk[4 * j + 1], pk[4 * j + 2], pk[4 * j + 3]);
    __syncthreads();   // P visible to all waves

    // ---- phase 4: MFMA. GEMM1: h^T = W1p . P^T ; GEMM2: upd^T = W2 . h^T ----
    bf16x8 pf[4][2];
    #pragma unroll
    for (int n = 0; n < 4; ++n) {
        int v = (4 * wv + n) * 16 + r16;
        #pragma unroll
        for (int ks = 0; ks < 2; ++ks)
            pf[n][ks] = *(const bf16x8*)(Ps + v * 72 + ks * 32 + g * 8);
    }

    f32x4 acc2[4] = {{0,0,0,0},{0,0,0,0},{0,0,0,0},{0,0,0,0}};
    const f32x4 z4 = {0,0,0,0};

    #pragma unroll
    for (int ch = 0; ch < 4; ++ch) {
        const bf16x8 aE0 = *(const bf16x8*)(wsW + ((ch * 4 + 0) * 64 + lane) * 8);
        const bf16x8 aE1 = *(const bf16x8*)(wsW + ((ch * 4 + 1) * 64 + lane) * 8);
        const bf16x8 aO0 = *(const bf16x8*)(wsW + ((ch * 4 + 2) * 64 + lane) * 8);
        const bf16x8 aO1 = *(const bf16x8*)(wsW + ((ch * 4 + 3) * 64 + lane) * 8);
        const bf16x8 w2f = *(const bf16x8*)(wsW + 8192 + (ch * 64 + lane) * 8);
        const float4 bE = *(const float4*)(b1 + ch * 32 + 8 * g);
        const float4 bO = *(const float4*)(b1 + ch * 32 + 8 * g + 4);

        #pragma unroll
        for (int n = 0; n < 4; ++n) {
            f32x4 accE, accO;
            accE = __builtin_amdgcn_mfma_f32_16x16x32_bf16(aE0, pf[n][0], z4, 0, 0, 0);
            accE = __builtin_amdgcn_mfma_f32_16x16x32_bf16(aE1, pf[n][1], accE, 0, 0, 0);
            accO = __builtin_amdgcn_mfma_f32_16x16x32_bf16(aO0, pf[n][0], z4, 0, 0, 0);
            accO = __builtin_amdgcn_mfma_f32_16x16x32_bf16(aO1, pf[n][1], accO, 0, 0, 0);
            bf16x8 hb;
            hb[0] = (short)f2bf(fmaxf(accE[0] + bE.x, 0.f));
            hb[1] = (short)f2bf(fmaxf(accE[1] + bE.y, 0.f));
            hb[2] = (short)f2bf(fmaxf(accE[2] + bE.z, 0.f));
            hb[3] = (short)f2bf(fmaxf(accE[3] + bE.w, 0.f));
            hb[4] = (short)f2bf(fmaxf(accO[0] + bO.x, 0.f));
            hb[5] = (short)f2bf(fmaxf(accO[1] + bO.y, 0.f));
            hb[6] = (short)f2bf(fmaxf(accO[2] + bO.z, 0.f));
            hb[7] = (short)f2bf(fmaxf(accO[3] + bO.w, 0.f));
            acc2[n] = __builtin_amdgcn_mfma_f32_16x16x32_bf16(w2f, hb, acc2[n], 0, 0, 0);
        }
    }

    // ---- phase 5: epilogue: out = x*alive + upd*(smask*alive), x center from Ps (bf16) ----
    #pragma unroll
    for (int n = 0; n < 4; ++n) {
        int v = (4 * wv + n) * 16 + r16;
        float al = aliveA[v], mu = msuA[v];
        int vx = v & 7, vy = (v >> 3) & 7;
        int gidx = xbase + (gz0 + wv) * 4096 + (gy0 + vy) * 64 + (gx0 + vx);
        #pragma unroll
        for (int reg = 0; reg < 4; ++reg) {
            int c = 4 * g + reg;
            unsigned short cs = Ps[v * 72 + 16 * g + 4 * reg];   // ident feature = center x
            float xc = __builtin_bit_cast(float, (unsigned)cs << 16);
            out[gidx + c * 262144] = xc * al + acc2[n][reg] * mu;
        }
    }
}

extern "C" void kernel_launch(void* const* d_in, const int* in_sizes, int n_in,
                              void* d_out, int out_size, void* d_ws, size_t ws_size,
                              hipStream_t stream)
{
    const float* x      = (const float*)d_in[0];
    const float* rand_u = (const float*)d_in[1];
    const float* w1     = (const float*)d_in[2];
    const float* b1     = (const float*)d_in[3];
    const float* w2     = (const float*)d_in[4];
    float* out = (float*)d_out;
    unsigned short* wsW = (unsigned short*)d_ws;   // 20.5 KB used

    permute_w<<<dim3(1), dim3(256), 0, stream>>>(w1, w2, wsW);

    dim3 grid(8, 8, 64);
    dim3 block(256);
    nca_fused<<<grid, block, 0, stream>>>(x, rand_u, wsW, b1, out);
}

// Round 9
// 230.874 us; speedup vs baseline: 1.6710x; 1.6710x over previous
//
#include <hip/hip_runtime.h>

#define TQY 10
#define TQX 10
#define QST 600        // 6*10*10 sites per quad
#define NSITES 2400    // 4 quads

// LDS map (bytes):
//  [0,19200)      quad tile uint2[2400]: [cq][z 6][y 10][x 10], 4 bf16 channels/site
//  [0,36864)      P bf16 rows (overlays tile after barrier 2), 144B row stride
//  [36864,37888)  alive[256] f32
//  [37888,38912)  msu[256] f32
//
// d_ws (shorts): [0,8192) W1 frags 1024x16B; [8192,10240) W2 frags 256x16B

typedef __attribute__((ext_vector_type(8))) short bf16x8;
typedef __attribute__((ext_vector_type(4))) float f32x4;

__device__ __forceinline__ unsigned short f2bf(float f) {
    unsigned u = __builtin_bit_cast(unsigned, f);
    u += 0x7FFFu + ((u >> 16) & 1u);          // RNE
    return (unsigned short)(u >> 16);
}
__device__ __forceinline__ float blo(unsigned u) { return __builtin_bit_cast(float, u << 16); }
__device__ __forceinline__ float bhi(unsigned u) { return __builtin_bit_cast(float, u & 0xffff0000u); }
__device__ __forceinline__ bf16x8 pack8f(float4 a, float4 b) {
    bf16x8 o;
    o[0] = (short)f2bf(a.x); o[1] = (short)f2bf(a.y);
    o[2] = (short)f2bf(a.z); o[3] = (short)f2bf(a.w);
    o[4] = (short)f2bf(b.x); o[5] = (short)f2bf(b.y);
    o[6] = (short)f2bf(b.z); o[7] = (short)f2bf(b.w);
    return o;
}

// ---- pre-pass: permute W1/W2 into lane-canonical bf16 MFMA fragments in d_ws ----
__global__ __launch_bounds__(256) void permute_w(
    const float* __restrict__ w1, const float* __restrict__ w2,
    unsigned short* __restrict__ wsW)
{
    const int t = threadIdx.x;
    #pragma unroll
    for (int j = 0; j < 4; ++j) {
        int w = t + 256 * j;                 // [0,1024)
        int lane = w & 63, f = (w >> 6) & 3, ch = w >> 8;
        int r16 = lane & 15, g = lane >> 4;
        int row = ch * 32 + 8 * (r16 >> 2) + (r16 & 3) + 4 * (f >> 1);  // E: +0, O: +4
        int col = (f & 1) * 32 + g * 8;                                  // ks half
        const float* src = w1 + row * 64 + col;
        bf16x8 v = pack8f(*(const float4*)src, *(const float4*)(src + 4));
        *(bf16x8*)(wsW + w * 8) = v;
    }
    {
        int w = t;                           // [0,256)
        int lane = w & 63, ch = w >> 6;
        int r16 = lane & 15, g = lane >> 4;
        const float* src = w2 + r16 * 128 + ch * 32 + g * 8;
        bf16x8 v = pack8f(*(const float4*)src, *(const float4*)(src + 4));
        *(bf16x8*)(wsW + 8192 + w * 8) = v;
    }
}

__global__ __launch_bounds__(256, 3) void nca_fused(
    const float* __restrict__ x, const float* __restrict__ rand_u,
    const unsigned short* __restrict__ wsW, const float* __restrict__ b1,
    float* __restrict__ out)
{
    __shared__ __align__(16) char smem[38912];
    uint2*          tq     = (uint2*)smem;
    unsigned short* Ps     = (unsigned short*)smem;       // after barrier 2
    float*          aliveA = (float*)(smem + 36864);
    float*          msuA   = (float*)(smem + 37888);

    const int tid = threadIdx.x;
    const int gx0 = blockIdx.x * 8, gy0 = blockIdx.y * 8;
    const int zb  = blockIdx.z;
    const int b   = zb >> 4, gz0 = (zb & 15) * 4;
    const int xbase = b * (16 * 262144);

    // ---- phase 1: stage channel-quad bf16 tile (zero halo) ----
    for (int i = tid; i < NSITES; i += 256) {
        int cq = i / QST, r = i - cq * QST;
        int z = r / 100, r2 = r - z * 100;
        int y = r2 / 10, xx = r2 - y * 10;
        int gz = gz0 + z - 1, gy = gy0 + y - 1, gxx = gx0 + xx - 1;
        uint2 w = make_uint2(0u, 0u);
        if ((unsigned)gz < 64u && (unsigned)gy < 64u && (unsigned)gxx < 64u) {
            const float* s = x + xbase + cq * (4 * 262144) + gz * 4096 + gy * 64 + gxx;
            w.x = (unsigned)f2bf(s[0])            | ((unsigned)f2bf(s[262144]) << 16);
            w.y = (unsigned)f2bf(s[2 * 262144])   | ((unsigned)f2bf(s[3 * 262144]) << 16);
        }
        tq[i] = w;
    }
    __syncthreads();

    // ---- phase 2: perception, separable Sobel on bf16 quads ----
    const int tx = tid & 7, ty = (tid >> 3) & 7, tz = tid >> 6;
    const int lane = tid & 63, wv = tid >> 6;
    const int g = lane >> 4, r16 = lane & 15;
    const int rowbase = (tz * TQY + ty) * TQX + tx;

    unsigned pk[32];
    float pool3 = -1e30f;

    #pragma unroll
    for (int cq = 0; cq < 4; ++cq) {
        float s1a[4], s2a[4], s3a[4];
        unsigned short ctrs[4];
        #pragma unroll
        for (int e = 0; e < 4; ++e) { s1a[e] = 0.f; s2a[e] = 0.f; s3a[e] = 0.f; }
        #pragma unroll
        for (int i2 = 0; i2 < 3; ++i2) {
            float A[4], Bv[4], Cv[4];
            #pragma unroll
            for (int e = 0; e < 4; ++e) { A[e] = 0.f; Bv[e] = 0.f; Cv[e] = 0.f; }
            #pragma unroll
            for (int j = 0; j < 3; ++j) {
                const uint2* rp = tq + cq * QST + i2 * 100 + j * 10 + rowbase;
                uint2 q0 = rp[0], q1 = rp[1], q2 = rp[2];
                float v0[4] = { blo(q0.x), bhi(q0.x), blo(q0.y), bhi(q0.y) };
                float v1[4] = { blo(q1.x), bhi(q1.x), blo(q1.y), bhi(q1.y) };
                float v2[4] = { blo(q2.x), bhi(q2.x), blo(q2.y), bhi(q2.y) };
                if (cq == 0)   // alpha (c=3) pool, reusing the same taps
                    pool3 = fmaxf(pool3, fmaxf(fmaxf(v0[3], v1[3]), v2[3]));
                if (i2 == 1 && j == 1) {   // center bf16 shorts (ident features)
                    ctrs[0] = (unsigned short)(q1.x & 0xffffu);
                    ctrs[1] = (unsigned short)(q1.x >> 16);
                    ctrs[2] = (unsigned short)(q1.y & 0xffffu);
                    ctrs[3] = (unsigned short)(q1.y >> 16);
                }
                const float wj = (j == 1) ? 2.f : 1.f;
                #pragma unroll
                for (int e = 0; e < 4; ++e) {
                    float rg = fmaf(2.f, v1[e], v0[e] + v2[e]);  // g_x
                    float rd = v2[e] - v0[e];                    // d_x
                    A[e]  = fmaf(wj, rg, A[e]);                  // g_y g_x
                    Cv[e] = fmaf(wj, rd, Cv[e]);                 // g_y d_x
                    if (j == 0) Bv[e] -= rg;                     // d_y g_x
                    if (j == 2) Bv[e] += rg;
                }
            }
            const float wi = (i2 == 1) ? 2.f : 1.f;
            #pragma unroll
            for (int e = 0; e < 4; ++e) {
                if (i2 == 0) s1a[e] -= A[e];                     // d_z (g_y g_x)
                if (i2 == 2) s1a[e] += A[e];
                s2a[e] = fmaf(wi, Bv[e], s2a[e]);                // g_z (d_y g_x)
                s3a[e] = fmaf(wi, Cv[e], s3a[e]);                // g_z (g_y d_x)
            }
        }
        #pragma unroll
        for (int e = 0; e < 4; ++e) {
            int c = 4 * cq + e;
            pk[2 * c]     = (unsigned)ctrs[e]                    | ((unsigned)f2bf(s1a[e] * 0.125f) << 16);
            pk[2 * c + 1] = (unsigned)f2bf(s2a[e] * 0.125f)      | ((unsigned)f2bf(s3a[e] * 0.125f) << 16);
        }
    }
    const float alive = (pool3 > 0.1f) ? 1.f : 0.f;
    const float ru = rand_u[b * 262144 + (gz0 + tz) * 4096 + (gy0 + ty) * 64 + (gx0 + tx)];
    aliveA[tid] = alive;
    msuA[tid]   = (ru <= 0.5f) ? alive : 0.f;
    __syncthreads();   // all waves done reading tile

    // ---- phase 3: write P (bf16) over the tile region ----
    uint4* prow = (uint4*)(smem + tid * 144);
    #pragma unroll
    for (int j = 0; j < 8; ++j)
        prow[j] = make_uint4(pk[4 * j], pk[4 * j + 1], pk[4 * j + 2], pk[4 * j + 3]);
    __syncthreads();   // P visible to all waves

    // ---- phase 4: MFMA. GEMM1: h^T = W1p . P^T ; GEMM2: upd^T = W2 . h^T ----
    bf16x8 pf[4][2];
    #pragma unroll
    for (int n = 0; n < 4; ++n) {
        int v = (4 * wv + n) * 16 + r16;
        #pragma unroll
        for (int ks = 0; ks < 2; ++ks)
            pf[n][ks] = *(const bf16x8*)(Ps + v * 72 + ks * 32 + g * 8);
    }

    f32x4 acc2[4] = {{0,0,0,0},{0,0,0,0},{0,0,0,0},{0,0,0,0}};
    const f32x4 z4 = {0,0,0,0};

    #pragma unroll
    for (int ch = 0; ch < 4; ++ch) {
        const bf16x8 aE0 = *(const bf16x8*)(wsW + ((ch * 4 + 0) * 64 + lane) * 8);
        const bf16x8 aE1 = *(const bf16x8*)(wsW + ((ch * 4 + 1) * 64 + lane) * 8);
        const bf16x8 aO0 = *(const bf16x8*)(wsW + ((ch * 4 + 2) * 64 + lane) * 8);
        const bf16x8 aO1 = *(const bf16x8*)(wsW + ((ch * 4 + 3) * 64 + lane) * 8);
        const bf16x8 w2f = *(const bf16x8*)(wsW + 8192 + (ch * 64 + lane) * 8);
        const float4 bE = *(const float4*)(b1 + ch * 32 + 8 * g);
        const float4 bO = *(const float4*)(b1 + ch * 32 + 8 * g + 4);

        #pragma unroll
        for (int n = 0; n < 4; ++n) {
            f32x4 accE, accO;
            accE = __builtin_amdgcn_mfma_f32_16x16x32_bf16(aE0, pf[n][0], z4, 0, 0, 0);
            accE = __builtin_amdgcn_mfma_f32_16x16x32_bf16(aE1, pf[n][1], accE, 0, 0, 0);
            accO = __builtin_amdgcn_mfma_f32_16x16x32_bf16(aO0, pf[n][0], z4, 0, 0, 0);
            accO = __builtin_amdgcn_mfma_f32_16x16x32_bf16(aO1, pf[n][1], accO, 0, 0, 0);
            bf16x8 hb;
            hb[0] = (short)f2bf(fmaxf(accE[0] + bE.x, 0.f));
            hb[1] = (short)f2bf(fmaxf(accE[1] + bE.y, 0.f));
            hb[2] = (short)f2bf(fmaxf(accE[2] + bE.z, 0.f));
            hb[3] = (short)f2bf(fmaxf(accE[3] + bE.w, 0.f));
            hb[4] = (short)f2bf(fmaxf(accO[0] + bO.x, 0.f));
            hb[5] = (short)f2bf(fmaxf(accO[1] + bO.y, 0.f));
            hb[6] = (short)f2bf(fmaxf(accO[2] + bO.z, 0.f));
            hb[7] = (short)f2bf(fmaxf(accO[3] + bO.w, 0.f));
            acc2[n] = __builtin_amdgcn_mfma_f32_16x16x32_bf16(w2f, hb, acc2[n], 0, 0, 0);
        }
    }

    // ---- phase 5: epilogue: out = x*alive + upd*(smask*alive), x center from Ps (bf16) ----
    #pragma unroll
    for (int n = 0; n < 4; ++n) {
        int v = (4 * wv + n) * 16 + r16;
        float al = aliveA[v], mu = msuA[v];
        int vx = v & 7, vy = (v >> 3) & 7;
        int gidx = xbase + (gz0 + wv) * 4096 + (gy0 + vy) * 64 + (gx0 + vx);
        #pragma unroll
        for (int reg = 0; reg < 4; ++reg) {
            int c = 4 * g + reg;
            unsigned short cs = Ps[v * 72 + 16 * g + 4 * reg];   // ident feature = center x
            float xc = __builtin_bit_cast(float, (unsigned)cs << 16);
            out[gidx + c * 262144] = xc * al + acc2[n][reg] * mu;
        }
    }
}

extern "C" void kernel_launch(void* const* d_in, const int* in_sizes, int n_in,
                              void* d_out, int out_size, void* d_ws, size_t ws_size,
                              hipStream_t stream)
{
    const float* x      = (const float*)d_in[0];
    const float* rand_u = (const float*)d_in[1];
    const float* w1     = (const float*)d_in[2];
    const float* b1     = (const float*)d_in[3];
    const float* w2     = (const float*)d_in[4];
    float* out = (float*)d_out;
    unsigned short* wsW = (unsigned short*)d_ws;   // 20.5 KB used

    permute_w<<<dim3(1), dim3(256), 0, stream>>>(w1, w2, wsW);

    dim3 grid(8, 8, 64);
    dim3 block(256);
    nca_fused<<<grid, block, 0, stream>>>(x, rand_u, wsW, b1, out);
}

// Round 10
// 147.594 us; speedup vs baseline: 2.6139x; 1.5643x over previous
//
#include <hip/hip_runtime.h>

#define QST 600        // 6*10*10 sites per quad
#define NSITES 2400    // 4 quads

// LDS map (bytes):
//  [0,19200)      quad tile uint2[2400]: [cq][z 6][y 10][x 10], 4 bf16 channels/site
//  [19200,51968)  P bf16: 256 rows x 128B, 16B-slot XOR swizzle (slot' = slot ^ (row&7))
//  [51968,52992)  alive[256] f32
//  [52992,54016)  msu[256] f32
//  total 54016 B -> 3 blocks/CU
//
// d_ws (shorts): [0,8192) W1 frags 1024x16B; [8192,10240) W2 frags 256x16B

typedef __attribute__((ext_vector_type(8))) short bf16x8;
typedef __attribute__((ext_vector_type(4))) float f32x4;

__device__ __forceinline__ unsigned short f2bf(float f) {
    unsigned u = __builtin_bit_cast(unsigned, f);
    u += 0x7FFFu + ((u >> 16) & 1u);          // RNE
    return (unsigned short)(u >> 16);
}
__device__ __forceinline__ float blo(unsigned u) { return __builtin_bit_cast(float, u << 16); }
__device__ __forceinline__ float bhi(unsigned u) { return __builtin_bit_cast(float, u & 0xffff0000u); }
__device__ __forceinline__ bf16x8 pack8f(float4 a, float4 b) {
    bf16x8 o;
    o[0] = (short)f2bf(a.x); o[1] = (short)f2bf(a.y);
    o[2] = (short)f2bf(a.z); o[3] = (short)f2bf(a.w);
    o[4] = (short)f2bf(b.x); o[5] = (short)f2bf(b.y);
    o[6] = (short)f2bf(b.z); o[7] = (short)f2bf(b.w);
    return o;
}

// ---- pre-pass: permute W1/W2 into lane-canonical bf16 MFMA fragments in d_ws ----
__global__ __launch_bounds__(256) void permute_w(
    const float* __restrict__ w1, const float* __restrict__ w2,
    unsigned short* __restrict__ wsW)
{
    const int t = threadIdx.x;
    #pragma unroll
    for (int j = 0; j < 4; ++j) {
        int w = t + 256 * j;                 // [0,1024)
        int lane = w & 63, f = (w >> 6) & 3, ch = w >> 8;
        int r16 = lane & 15, g = lane >> 4;
        int row = ch * 32 + 8 * (r16 >> 2) + (r16 & 3) + 4 * (f >> 1);  // E: +0, O: +4
        int col = (f & 1) * 32 + g * 8;                                  // ks half
        const float* src = w1 + row * 64 + col;
        bf16x8 v = pack8f(*(const float4*)src, *(const float4*)(src + 4));
        *(bf16x8*)(wsW + w * 8) = v;
    }
    {
        int w = t;                           // [0,256)
        int lane = w & 63, ch = w >> 6;
        int r16 = lane & 15, g = lane >> 4;
        const float* src = w2 + r16 * 128 + ch * 32 + g * 8;
        bf16x8 v = pack8f(*(const float4*)src, *(const float4*)(src + 4));
        *(bf16x8*)(wsW + 8192 + w * 8) = v;
    }
}

__global__ __launch_bounds__(256, 3) void nca_fused(
    const float* __restrict__ x, const float* __restrict__ rand_u,
    const unsigned short* __restrict__ wsW, const float* __restrict__ b1,
    float* __restrict__ out)
{
    __shared__ __align__(16) char smem[54016];
    uint2*          tq     = (uint2*)smem;
    unsigned short* Ps     = (unsigned short*)(smem + 19200);
    float*          aliveA = (float*)(smem + 51968);
    float*          msuA   = (float*)(smem + 52992);

    const int tid = threadIdx.x;
    const int gx0 = blockIdx.x * 8, gy0 = blockIdx.y * 8;
    const int zb  = blockIdx.z;
    const int b   = zb >> 4, gz0 = (zb & 15) * 4;
    const int xbase = b * (16 * 262144);

    // ---- phase 1: stage channel-quad bf16 tile (zero halo) ----
    for (int i = tid; i < NSITES; i += 256) {
        int cq = i / QST, r = i - cq * QST;
        int z = r / 100, r2 = r - z * 100;
        int y = r2 / 10, xx = r2 - y * 10;
        int gz = gz0 + z - 1, gy = gy0 + y - 1, gxx = gx0 + xx - 1;
        uint2 w = make_uint2(0u, 0u);
        if ((unsigned)gz < 64u && (unsigned)gy < 64u && (unsigned)gxx < 64u) {
            const float* s = x + xbase + cq * (4 * 262144) + gz * 4096 + gy * 64 + gxx;
            w.x = (unsigned)f2bf(s[0])            | ((unsigned)f2bf(s[262144]) << 16);
            w.y = (unsigned)f2bf(s[2 * 262144])   | ((unsigned)f2bf(s[3 * 262144]) << 16);
        }
        tq[i] = w;
    }
    __syncthreads();

    // ---- phase 2: perception (separable Sobel on bf16 quads), P written per-cq ----
    const int tx = tid & 7, ty = (tid >> 3) & 7, tz = tid >> 6;
    const int lane = tid & 63, wv = tid >> 6;
    const int g = lane >> 4, r16 = lane & 15;
    const int rowbase = (tz * 10 + ty) * 10 + tx;

    float pool3 = -1e30f;

    #pragma unroll
    for (int cq = 0; cq < 4; ++cq) {
        float s1a[4], s2a[4], s3a[4];
        unsigned short ctrs[4];
        #pragma unroll
        for (int e = 0; e < 4; ++e) { s1a[e] = 0.f; s2a[e] = 0.f; s3a[e] = 0.f; }
        #pragma unroll
        for (int i2 = 0; i2 < 3; ++i2) {
            float A[4], Bv[4], Cv[4];
            #pragma unroll
            for (int e = 0; e < 4; ++e) { A[e] = 0.f; Bv[e] = 0.f; Cv[e] = 0.f; }
            #pragma unroll
            for (int j = 0; j < 3; ++j) {
                const uint2* rp = tq + cq * QST + i2 * 100 + j * 10 + rowbase;
                uint2 q0 = rp[0], q1 = rp[1], q2 = rp[2];
                float v0[4] = { blo(q0.x), bhi(q0.x), blo(q0.y), bhi(q0.y) };
                float v1[4] = { blo(q1.x), bhi(q1.x), blo(q1.y), bhi(q1.y) };
                float v2[4] = { blo(q2.x), bhi(q2.x), blo(q2.y), bhi(q2.y) };
                if (cq == 0)   // alpha (c=3) pool, reusing the same taps
                    pool3 = fmaxf(pool3, fmaxf(fmaxf(v0[3], v1[3]), v2[3]));
                if (i2 == 1 && j == 1) {   // center bf16 shorts (ident features)
                    ctrs[0] = (unsigned short)(q1.x & 0xffffu);
                    ctrs[1] = (unsigned short)(q1.x >> 16);
                    ctrs[2] = (unsigned short)(q1.y & 0xffffu);
                    ctrs[3] = (unsigned short)(q1.y >> 16);
                }
                const float wj = (j == 1) ? 2.f : 1.f;
                #pragma unroll
                for (int e = 0; e < 4; ++e) {
                    float rg = fmaf(2.f, v1[e], v0[e] + v2[e]);  // g_x
                    float rd = v2[e] - v0[e];                    // d_x
                    A[e]  = fmaf(wj, rg, A[e]);                  // g_y g_x
                    Cv[e] = fmaf(wj, rd, Cv[e]);                 // g_y d_x
                    if (j == 0) Bv[e] -= rg;                     // d_y g_x
                    if (j == 2) Bv[e] += rg;
                }
            }
            const float wi = (i2 == 1) ? 2.f : 1.f;
            #pragma unroll
            for (int e = 0; e < 4; ++e) {
                if (i2 == 0) s1a[e] -= A[e];                     // d_z (g_y g_x)
                if (i2 == 2) s1a[e] += A[e];
                s2a[e] = fmaf(wi, Bv[e], s2a[e]);                // g_z (d_y g_x)
                s3a[e] = fmaf(wi, Cv[e], s3a[e]);                // g_z (g_y d_x)
            }
        }
        // pack this cq's 8 P-dwords and write NOW (no overlay -> no wait)
        unsigned pk8[8];
        #pragma unroll
        for (int e = 0; e < 4; ++e) {
            pk8[2 * e]     = (unsigned)ctrs[e]               | ((unsigned)f2bf(s1a[e] * 0.125f) << 16);
            pk8[2 * e + 1] = (unsigned)f2bf(s2a[e] * 0.125f) | ((unsigned)f2bf(s3a[e] * 0.125f) << 16);
        }
        int s0 = (2 * cq)     ^ (tid & 7);
        int s1 = (2 * cq + 1) ^ (tid & 7);
        *(uint4*)(smem + 19200 + tid * 128 + s0 * 16) = make_uint4(pk8[0], pk8[1], pk8[2], pk8[3]);
        *(uint4*)(smem + 19200 + tid * 128 + s1 * 16) = make_uint4(pk8[4], pk8[5], pk8[6], pk8[7]);
    }
    const float alive = (pool3 > 0.1f) ? 1.f : 0.f;
    const float ru = rand_u[b * 262144 + (gz0 + tz) * 4096 + (gy0 + ty) * 64 + (gx0 + tx)];
    aliveA[tid] = alive;
    msuA[tid]   = (ru <= 0.5f) ? alive : 0.f;
    __syncthreads();   // P + masks visible to all waves

    // ---- phase 3: MFMA. GEMM1: h^T = W1p . P^T ; GEMM2: upd^T = W2 . h^T ----
    bf16x8 pf[4][2];
    #pragma unroll
    for (int n = 0; n < 4; ++n) {
        int v = (4 * wv + n) * 16 + r16;
        #pragma unroll
        for (int ks = 0; ks < 2; ++ks) {
            int sl = (ks * 4 + g) ^ (r16 & 7);     // slot-XOR swizzle (row&7 == r16&7)
            pf[n][ks] = *(const bf16x8*)(Ps + v * 64 + sl * 8);
        }
    }

    f32x4 acc2[4] = {{0,0,0,0},{0,0,0,0},{0,0,0,0},{0,0,0,0}};
    const f32x4 z4 = {0,0,0,0};

    #pragma unroll
    for (int ch = 0; ch < 4; ++ch) {
        const bf16x8 aE0 = *(const bf16x8*)(wsW + ((ch * 4 + 0) * 64 + lane) * 8);
        const bf16x8 aE1 = *(const bf16x8*)(wsW + ((ch * 4 + 1) * 64 + lane) * 8);
        const bf16x8 aO0 = *(const bf16x8*)(wsW + ((ch * 4 + 2) * 64 + lane) * 8);
        const bf16x8 aO1 = *(const bf16x8*)(wsW + ((ch * 4 + 3) * 64 + lane) * 8);
        const bf16x8 w2f = *(const bf16x8*)(wsW + 8192 + (ch * 64 + lane) * 8);
        const float4 bE = *(const float4*)(b1 + ch * 32 + 8 * g);
        const float4 bO = *(const float4*)(b1 + ch * 32 + 8 * g + 4);

        #pragma unroll
        for (int n = 0; n < 4; ++n) {
            f32x4 accE, accO;
            accE = __builtin_amdgcn_mfma_f32_16x16x32_bf16(aE0, pf[n][0], z4, 0, 0, 0);
            accE = __builtin_amdgcn_mfma_f32_16x16x32_bf16(aE1, pf[n][1], accE, 0, 0, 0);
            accO = __builtin_amdgcn_mfma_f32_16x16x32_bf16(aO0, pf[n][0], z4, 0, 0, 0);
            accO = __builtin_amdgcn_mfma_f32_16x16x32_bf16(aO1, pf[n][1], accO, 0, 0, 0);
            bf16x8 hb;
            hb[0] = (short)f2bf(fmaxf(accE[0] + bE.x, 0.f));
            hb[1] = (short)f2bf(fmaxf(accE[1] + bE.y, 0.f));
            hb[2] = (short)f2bf(fmaxf(accE[2] + bE.z, 0.f));
            hb[3] = (short)f2bf(fmaxf(accE[3] + bE.w, 0.f));
            hb[4] = (short)f2bf(fmaxf(accO[0] + bO.x, 0.f));
            hb[5] = (short)f2bf(fmaxf(accO[1] + bO.y, 0.f));
            hb[6] = (short)f2bf(fmaxf(accO[2] + bO.z, 0.f));
            hb[7] = (short)f2bf(fmaxf(accO[3] + bO.w, 0.f));
            acc2[n] = __builtin_amdgcn_mfma_f32_16x16x32_bf16(w2f, hb, acc2[n], 0, 0, 0);
        }
    }

    // ---- phase 4: epilogue: out = x*alive + upd*(smask*alive), x center from Ps (bf16) ----
    #pragma unroll
    for (int n = 0; n < 4; ++n) {
        int v = (4 * wv + n) * 16 + r16;
        float al = aliveA[v], mu = msuA[v];
        int vx = v & 7, vy = (v >> 3) & 7;
        int gidx = xbase + (gz0 + wv) * 4096 + (gy0 + vy) * 64 + (gx0 + vx);
        #pragma unroll
        for (int reg = 0; reg < 4; ++reg) {
            int c = 4 * g + reg;
            int sl = (2 * g + (reg >> 1)) ^ (r16 & 7);           // ident dword 2c = slot 2g+(reg>>1)
            unsigned short cs = Ps[v * 64 + sl * 8 + 4 * (reg & 1)];
            float xc = __builtin_bit_cast(float, (unsigned)cs << 16);
            out[gidx + c * 262144] = xc * al + acc2[n][reg] * mu;
        }
    }
}

extern "C" void kernel_launch(void* const* d_in, const int* in_sizes, int n_in,
                              void* d_out, int out_size, void* d_ws, size_t ws_size,
                              hipStream_t stream)
{
    const float* x      = (const float*)d_in[0];
    const float* rand_u = (const float*)d_in[1];
    const float* w1     = (const float*)d_in[2];
    const float* b1     = (const float*)d_in[3];
    const float* w2     = (const float*)d_in[4];
    float* out = (float*)d_out;
    unsigned short* wsW = (unsigned short*)d_ws;   // 20.5 KB used

    permute_w<<<dim3(1), dim3(256), 0, stream>>>(w1, w2, wsW);

    dim3 grid(8, 8, 64);
    dim3 block(256);
    nca_fused<<<grid, block, 0, stream>>>(x, rand_u, wsW, b1, out);
}